// Round 11
// baseline (49.928 us; speedup 1.0000x reference)
//
#include <hip/hip_runtime.h>

typedef __attribute__((ext_vector_type(8))) __bf16 bf16x8;
typedef __attribute__((ext_vector_type(4))) float f32x4;

#define NB 16
#define CIN 64
#define CT 69
#define NO 128
#define HWSZ 1024
#define OUTC 133

// round-to-nearest-even fp32 -> bf16 pair packed into u32 (lo = first)
__device__ __forceinline__ unsigned pack_bf16(float a, float b) {
    unsigned ua = __float_as_uint(a);
    ua += 0x7fffu + ((ua >> 16) & 1u);
    unsigned ub = __float_as_uint(b);
    ub += 0x7fffu + ((ub >> 16) & 1u);
    return (ua >> 16) | (ub & 0xffff0000u);
}

// value of a after round-to-nearest-even bf16 quantization
__device__ __forceinline__ float bf16rt(float a) {
    unsigned u = __float_as_uint(a);
    u += 0x7fffu + ((u >> 16) & 1u);
    return __uint_as_float(u & 0xffff0000u);
}

__device__ __forceinline__ void gload16(const void* g, void* l) {
    __builtin_amdgcn_global_load_lds(
        (const __attribute__((address_space(1))) unsigned int*)g,
        (__attribute__((address_space(3))) unsigned int*)l, 16, 0, 0);
}

// ---------------------------------------------------------------------------
// D1: prep only (sdw moved to D2's grid).
// blocks 0..255   : xT bf16 swizzle prep
// blocks 256..263 : wT bf16 swizzle prep
// blocks 264..303 : passthrough channels 128..132
// ---------------------------------------------------------------------------
__global__ __launch_bounds__(512) void prep_kernel(
    const float* __restrict__ x, const float* __restrict__ cw,
    unsigned* __restrict__ xT, unsigned* __restrict__ wT,
    float* __restrict__ out)
{
    int bl = blockIdx.x;
    int tid = threadIdx.x;

    if (bl < 256) {
        int v = bl * 512 + tid;             // 0..131071
        int blk2 = v >> 8;                  // b*32 + h
        int t2 = v & 255;
        int b = blk2 >> 5, h = blk2 & 31;
        int w = t2 & 31, cp0 = t2 >> 5;
        const float* xr = x + (((size_t)b * CT) << 10) + h * 32 + w;
        unsigned* dst = xT + (size_t)blk2 * 1024 + w * 32;
        int sw = (w & 7) << 2;
#pragma unroll
        for (int r = 0; r < 4; ++r) {
            int cp = cp0 + r * 8;
            dst[cp ^ sw] = pack_bf16(xr[(size_t)(2 * cp) << 10],
                                     xr[(size_t)(2 * cp + 1) << 10]);
        }
    } else if (bl < 264) {
        int tg = (bl - 256) * 512 + tid;    // 0..4095
        int o = tg >> 5, cp = tg & 31;
        int sw = (o & 7) << 2;
#pragma unroll
        for (int tap = 0; tap < 9; ++tap) {
            float v0 = cw[((size_t)o * CIN + 2 * cp) * 9 + tap];
            float v1 = cw[((size_t)o * CIN + 2 * cp + 1) * 9 + tap];
            wT[tap * 4096 + o * 32 + (cp ^ sw)] = pack_bf16(v0, v1);
        }
    } else {
        int idx = (bl - 264) * 512 + tid;   // 0..20479 quads
        int q = idx & 255;
        int c = (idx >> 8) % 5;
        int b = (idx >> 8) / 5;
        ((float4*)out)[((size_t)b * OUTC + NO + c) * 256 + q] =
            ((const float4*)x)[((size_t)b * CT + CIN + c) * 256 + q];
    }
}

// ---------------------------------------------------------------------------
// sdw body (r10-proven), isolated in a __noinline__ function so its register
// allocation doesn't interact with the conv/MFMA path (r3/r5 spill trigger).
// asm "+v" pins force win[] into VGPRs regardless.
// ---------------------------------------------------------------------------
__device__ __noinline__ void sdw_body(
    const float* __restrict__ x, const float* __restrict__ sk,
    unsigned short* __restrict__ sdwb, float* __restrict__ sdwpart,
    int sbl, int tid)
{
    int chg = sbl >> 5;              // 0..15 (channel group of 8)
    int slice = sbl & 31;            // 0..31
    int pix = slice * 512 + tid;     // 0..16383
    int b = pix >> 10;
    int hw = pix & 1023;
    int h = hw >> 5, w = hw & 31;

    float win[45];
#pragma unroll
    for (int ch = 0; ch < 5; ++ch) {
        const float* xb = x + (((size_t)b * CT + CIN + ch) << 10);
#pragma unroll
        for (int ki = 0; ki < 3; ++ki) {
            int rr = h + ki - 1;
            rr = rr < 0 ? 0 : (rr > 31 ? 31 : rr);
            const float* rp = xb + (rr << 5);
#pragma unroll
            for (int kj = 0; kj < 3; ++kj) {
                int cc = w + kj - 1;
                cc = cc < 0 ? 0 : (cc > 31 ? 31 : cc);
                win[ch * 9 + ki * 3 + kj] = rp[cc];
            }
        }
    }
#pragma unroll
    for (int ch = 0; ch < 2; ++ch) {
        float c = win[ch * 9 + 4];
#pragma unroll
        for (int k = 0; k < 9; ++k) win[ch * 9 + k] -= c;
    }
#pragma unroll
    for (int q = 0; q < 45; ++q) asm volatile("" : "+v"(win[q]));

    int wid = tid >> 6;
    int wslot = slice * 8 + wid;     // 0..255 per channel
    for (int j = 0; j < 8; ++j) {
        int ch = chg * 8 + j;        // uniform across the block
        const float* kk = sk + (size_t)ch * 45;
        float s = 0.f;
#pragma unroll
        for (int q = 0; q < 45; ++q) s += fabsf(win[q] - kk[q]);
        unsigned u = __float_as_uint(s);
        u += 0x7fffu + ((u >> 16) & 1u);
        sdwb[(((size_t)b * NO + ch) << 10) + hw] = (unsigned short)(u >> 16);
        float sr = __uint_as_float(u & 0xffff0000u);
        float ps = sr, ps2 = sr * sr;
#pragma unroll
        for (int off = 32; off; off >>= 1) {
            ps  += __shfl_xor(ps, off);
            ps2 += __shfl_xor(ps2, off);
        }
        if ((tid & 63) == 0) {
            sdwpart[((size_t)ch * 256 + wslot) * 2]     = ps;
            sdwpart[((size_t)ch * 256 + wslot) * 2 + 1] = ps2;
        }
    }
}

// ---------------------------------------------------------------------------
// D2: mixed grid. Blocks 0..255: conv (r10's pipelined MFMA, verbatim);
// blocks 256..767: sdw. conv is 1 resident block/CU (64 KB LDS); sdw blocks
// (no LDS use) fill the second slot -> 16 waves/CU during conv.
// ---------------------------------------------------------------------------
__global__ __launch_bounds__(512) void convsdw_kernel(
    const char* __restrict__ xT, const char* __restrict__ wT,
    const float* __restrict__ x, const float* __restrict__ sk,
    unsigned short* __restrict__ convb, float* __restrict__ convpart,
    unsigned short* __restrict__ sdwb, float* __restrict__ sdwpart)
{
    __shared__ __align__(16) char smem[65536];
    int tid = threadIdx.x;

    if (blockIdx.x >= 256) {
        sdw_body(x, sk, sdwb, sdwpart, blockIdx.x - 256, tid);
        return;
    }

    char* Xs = smem;                    // 16 KB
    char* Wb0 = smem + 16384;           // 3 x 16 KB W ring
    char* Wb1 = smem + 32768;
    char* Wb2 = smem + 49152;

    int bid = blockIdx.x;
    int b = bid >> 4;
    int h0 = (bid & 15) * 2;

    int lane = tid & 63;
    int wid = tid >> 6;
    int lo = lane & 15, g = lane >> 4;
    int ks = wid >> 2;
    int mg = (wid >> 1) & 1;
    int ng = wid & 1;

    // ---- prologue: stage X, W0, W1 (6 outstanding loads per thread) ----
#pragma unroll
    for (int q = 0; q < 2; ++q) {
        int ch = wid * 2 + q;
        int s = ch >> 2;
        int srch = h0 - 1 + s; srch = srch < 0 ? 0 : (srch > 31 ? 31 : srch);
        gload16(xT + ((size_t)(b * 32 + srch)) * 4096 + (ch & 3) * 1024 + lane * 16,
                Xs + ch * 1024);
    }
#pragma unroll
    for (int q = 0; q < 2; ++q) {
        int ch = wid * 2 + q;
        gload16(wT + ch * 1024 + lane * 16, Wb0 + ch * 1024);
    }
#pragma unroll
    for (int q = 0; q < 2; ++q) {
        int ch = wid * 2 + q;
        gload16(wT + 16384 + ch * 1024 + lane * 16, Wb1 + ch * 1024);
    }

    int acol[2][3];
#pragma unroll
    for (int i = 0; i < 2; ++i)
#pragma unroll
        for (int kj = 0; kj < 3; ++kj) {
            int cin = i * 16 + lo + kj - 1;
            cin = cin < 0 ? 0 : (cin > 31 ? 31 : cin);
            acol[i][kj] = cin * 128 + ((ks * 64 + g * 16) ^ ((cin & 7) << 4));
        }
    int boff[4];
#pragma unroll
    for (int n = 0; n < 4; ++n) {
        int o = ng * 64 + n * 16 + lo;
        boff[n] = o * 128 + ((ks * 64 + g * 16) ^ ((o & 7) << 4));
    }

    f32x4 acc[2][4];
#pragma unroll
    for (int i = 0; i < 2; ++i)
#pragma unroll
        for (int n = 0; n < 4; ++n) acc[i][n] = (f32x4){0.f, 0.f, 0.f, 0.f};

    // ---- pipelined K-loop over 9 taps (counted vmcnt, W ring) ----
#pragma unroll
    for (int tap = 0; tap < 9; ++tap) {
        int ki = tap / 3, kj = tap % 3;
        if (tap == 8) asm volatile("s_waitcnt vmcnt(0)" ::: "memory");
        else          asm volatile("s_waitcnt vmcnt(2)" ::: "memory");
        __builtin_amdgcn_sched_barrier(0);
        __builtin_amdgcn_s_barrier();
        __builtin_amdgcn_sched_barrier(0);
        if (tap + 2 < 9) {
            char* wn = ((tap + 2) % 3 == 0) ? Wb0 : ((tap + 2) % 3 == 1) ? Wb1 : Wb2;
#pragma unroll
            for (int q = 0; q < 2; ++q) {
                int ch = wid * 2 + q;
                gload16(wT + (size_t)(tap + 2) * 16384 + ch * 1024 + lane * 16,
                        wn + ch * 1024);
            }
        }
        const char* wc = (tap % 3 == 0) ? Wb0 : (tap % 3 == 1) ? Wb1 : Wb2;
        bf16x8 a0 = *(const bf16x8*)(Xs + (mg + ki) * 4096 + acol[0][kj]);
        bf16x8 a1 = *(const bf16x8*)(Xs + (mg + ki) * 4096 + acol[1][kj]);
#pragma unroll
        for (int n = 0; n < 4; ++n) {
            bf16x8 bv = *(const bf16x8*)(wc + boff[n]);
            acc[0][n] = __builtin_amdgcn_mfma_f32_16x16x32_bf16(a0, bv, acc[0][n], 0, 0, 0);
            acc[1][n] = __builtin_amdgcn_mfma_f32_16x16x32_bf16(a1, bv, acc[1][n], 0, 0, 0);
        }
    }
    __syncthreads();

    // ---- epilogue: combine ci-halves via LDS, store bf16, BN partials ----
    float* T = (float*)smem;   // [64][129] f32 = 33 KB (ring buffers dead)
    if (ks == 1) {
#pragma unroll
        for (int i = 0; i < 2; ++i)
#pragma unroll
            for (int n = 0; n < 4; ++n)
#pragma unroll
                for (int r = 0; r < 4; ++r) {
                    int pixel = (mg * 2 + i) * 16 + g * 4 + r;
                    int o = ng * 64 + n * 16 + lo;
                    T[pixel * 129 + o] = acc[i][n][r];
                }
    }
    __syncthreads();
    if (ks == 0) {
#pragma unroll
        for (int i = 0; i < 2; ++i)
#pragma unroll
            for (int n = 0; n < 4; ++n)
#pragma unroll
                for (int r = 0; r < 4; ++r) {
                    int pixel = (mg * 2 + i) * 16 + g * 4 + r;
                    int o = ng * 64 + n * 16 + lo;
                    T[pixel * 129 + o] += acc[i][n][r];
                }
    }
    __syncthreads();
    unsigned short* cbase = convb + (((size_t)b * NO) << 10) + h0 * 32;
#pragma unroll
    for (int r = 0; r < 4; ++r) {
        int o = r * 32 + (tid >> 4);
        int pq = tid & 15;
        float4 v;
        v.x = T[(pq * 4 + 0) * 129 + o];
        v.y = T[(pq * 4 + 1) * 129 + o];
        v.z = T[(pq * 4 + 2) * 129 + o];
        v.w = T[(pq * 4 + 3) * 129 + o];
        uint2 pk;
        pk.x = pack_bf16(v.x, v.y);
        pk.y = pack_bf16(v.z, v.w);
        *(uint2*)(cbase + ((size_t)o << 10) + pq * 4) = pk;
        float rx = bf16rt(v.x), ry = bf16rt(v.y);
        float rz = bf16rt(v.z), rw = bf16rt(v.w);
        float s  = rx + ry + rz + rw;
        float s2 = rx * rx + ry * ry + rz * rz + rw * rw;
#pragma unroll
        for (int off = 1; off < 16; off <<= 1) {
            s  += __shfl_xor(s, off);
            s2 += __shfl_xor(s2, off);
        }
        if (pq == 0) {
            convpart[((size_t)o * 256 + bid) * 2]     = s;
            convpart[((size_t)o * 256 + bid) * 2 + 1] = s2;
        }
    }
}

// ---------------------------------------------------------------------------
// D3: per-block stats reduce (8 channels) + fused BN/relu finalize reading
// bf16 conv/sdw (uint4 = 8 bf16), writing fp32 out once. (r10, proven)
// ---------------------------------------------------------------------------
__global__ __launch_bounds__(512) void final_kernel(
    const unsigned short* __restrict__ sdwb,
    const unsigned short* __restrict__ convb,
    const float* __restrict__ convpart, const float* __restrict__ sdwpart,
    float* __restrict__ out)
{
    __shared__ float st[32];      // [8][4]: cm, cis, sm, sis
    int bl = blockIdx.x;
    int tid = threadIdx.x;
    int b = bl >> 4;
    int o0 = (bl & 15) * 8;

    int lane = tid & 63;
    int wid = tid >> 6;           // wave wid reduces channel o0+wid
    {
        int ch = o0 + wid;
        double cs = 0.0, cs2 = 0.0, ss = 0.0, ss2 = 0.0;
#pragma unroll
        for (int q = 0; q < 4; ++q) {
            int slot = lane + q * 64;
            const float* cp = convpart + ((size_t)ch * 256 + slot) * 2;
            cs  += cp[0]; cs2 += cp[1];
            const float* sp = sdwpart + ((size_t)ch * 256 + slot) * 2;
            ss  += sp[0]; ss2 += sp[1];
        }
#pragma unroll
        for (int off = 32; off; off >>= 1) {
            cs  += __shfl_down(cs, off);
            cs2 += __shfl_down(cs2, off);
            ss  += __shfl_down(ss, off);
            ss2 += __shfl_down(ss2, off);
        }
        if (lane == 0) {
            double n = 16384.0;
            double cm = cs / n, cv = cs2 / n - cm * cm;
            double sm = ss / n, sv = ss2 / n - sm * sm;
            st[wid * 4]     = (float)cm;
            st[wid * 4 + 1] = (float)(1.0 / sqrt(cv + 1e-5));
            st[wid * 4 + 2] = (float)sm;
            st[wid * 4 + 3] = (float)(1.0 / sqrt(sv + 1e-5));
        }
    }
    __syncthreads();

#pragma unroll
    for (int k = 0; k < 2; ++k) {
        int ql = tid + k * 512;        // 0..1023
        int pl = ql >> 7;              // 0..7 -> channel
        int g8 = ql & 127;             // group of 8 pixels
        int o = o0 + pl;
        size_t ebase = (((size_t)b * NO + o) << 10) + g8 * 8;
        uint4 cu = *(const uint4*)(convb + ebase);
        uint4 su = *(const uint4*)(sdwb + ebase);
        float cm = st[pl * 4], cis = st[pl * 4 + 1];
        float sm = st[pl * 4 + 2], sis = st[pl * 4 + 3];
        float4 r0, r1;
        float cv, sv, mu, v;
        unsigned uc, us;
        uc = cu.x; us = su.x;
        cv = __uint_as_float(uc << 16); sv = __uint_as_float(us << 16);
        mu = (sv - sm) * sis; mu = mu > 0.f ? mu : 0.f;
        v = (cv - cm) * cis - mu; r0.x = v > 0.f ? v : 0.f;
        cv = __uint_as_float(uc & 0xffff0000u); sv = __uint_as_float(us & 0xffff0000u);
        mu = (sv - sm) * sis; mu = mu > 0.f ? mu : 0.f;
        v = (cv - cm) * cis - mu; r0.y = v > 0.f ? v : 0.f;
        uc = cu.y; us = su.y;
        cv = __uint_as_float(uc << 16); sv = __uint_as_float(us << 16);
        mu = (sv - sm) * sis; mu = mu > 0.f ? mu : 0.f;
        v = (cv - cm) * cis - mu; r0.z = v > 0.f ? v : 0.f;
        cv = __uint_as_float(uc & 0xffff0000u); sv = __uint_as_float(us & 0xffff0000u);
        mu = (sv - sm) * sis; mu = mu > 0.f ? mu : 0.f;
        v = (cv - cm) * cis - mu; r0.w = v > 0.f ? v : 0.f;
        uc = cu.z; us = su.z;
        cv = __uint_as_float(uc << 16); sv = __uint_as_float(us << 16);
        mu = (sv - sm) * sis; mu = mu > 0.f ? mu : 0.f;
        v = (cv - cm) * cis - mu; r1.x = v > 0.f ? v : 0.f;
        cv = __uint_as_float(uc & 0xffff0000u); sv = __uint_as_float(us & 0xffff0000u);
        mu = (sv - sm) * sis; mu = mu > 0.f ? mu : 0.f;
        v = (cv - cm) * cis - mu; r1.y = v > 0.f ? v : 0.f;
        uc = cu.w; us = su.w;
        cv = __uint_as_float(uc << 16); sv = __uint_as_float(us << 16);
        mu = (sv - sm) * sis; mu = mu > 0.f ? mu : 0.f;
        v = (cv - cm) * cis - mu; r1.z = v > 0.f ? v : 0.f;
        cv = __uint_as_float(uc & 0xffff0000u); sv = __uint_as_float(us & 0xffff0000u);
        mu = (sv - sm) * sis; mu = mu > 0.f ? mu : 0.f;
        v = (cv - cm) * cis - mu; r1.w = v > 0.f ? v : 0.f;
        float* ob = out + (((size_t)b * OUTC + o) << 10) + g8 * 8;
        *(float4*)ob = r0;
        *(float4*)(ob + 4) = r1;
    }
}

extern "C" void kernel_launch(void* const* d_in, const int* in_sizes, int n_in,
                              void* d_out, int out_size, void* d_ws, size_t ws_size,
                              hipStream_t stream)
{
    const float* x  = (const float*)d_in[0];
    const float* cw = (const float*)d_in[1];
    const float* sk = (const float*)d_in[3];
    float* out = (float*)d_out;

    unsigned short* sdwb  = (unsigned short*)d_ws;                     // 4 MB
    unsigned short* convb = (unsigned short*)((char*)d_ws + 0x400000); // 4 MB
    unsigned* xT       = (unsigned*)((char*)d_ws + 0x810000);   // 2 MB
    unsigned* wT       = (unsigned*)((char*)d_ws + 0xA10000);   // 144 KB
    float*    convpart = (float*)((char*)d_ws + 0xA40000);      // 256 KB
    float*    sdwpart  = (float*)((char*)d_ws + 0xA80000);      // 256 KB

    prep_kernel   <<<304, 512, 0, stream>>>(x, cw, xT, wT, out);
    convsdw_kernel<<<768, 512, 0, stream>>>((const char*)xT, (const char*)wT,
                                            x, sk, convb, convpart, sdwb, sdwpart);
    final_kernel  <<<256, 512, 0, stream>>>(sdwb, convb, convpart, sdwpart, out);
}

// Round 12
// 30.595 us; speedup vs baseline: 1.6319x; 1.6319x over previous
//
#include <hip/hip_runtime.h>

typedef __attribute__((ext_vector_type(8))) __bf16 bf16x8;
typedef __attribute__((ext_vector_type(4))) float f32x4;

#define NB 16
#define CIN 64
#define CT 69
#define NO 128
#define HWSZ 1024
#define OUTC 133

// round-to-nearest-even fp32 -> bf16 pair packed into u32 (lo = first)
__device__ __forceinline__ unsigned pack_bf16(float a, float b) {
    unsigned ua = __float_as_uint(a);
    ua += 0x7fffu + ((ua >> 16) & 1u);
    unsigned ub = __float_as_uint(b);
    ub += 0x7fffu + ((ub >> 16) & 1u);
    return (ua >> 16) | (ub & 0xffff0000u);
}

// value of a after round-to-nearest-even bf16 quantization
__device__ __forceinline__ float bf16rt(float a) {
    unsigned u = __float_as_uint(a);
    u += 0x7fffu + ((u >> 16) & 1u);
    return __uint_as_float(u & 0xffff0000u);
}

__device__ __forceinline__ void gload16(const void* g, void* l) {
    __builtin_amdgcn_global_load_lds(
        (const __attribute__((address_space(1))) unsigned int*)g,
        (__attribute__((address_space(3))) unsigned int*)l, 16, 0, 0);
}

// ---------------------------------------------------------------------------
// D1: prep + sdw (bf16 sdw store; partials from ROUNDED values so BN is
// self-consistent). Block-branched, NO MFMA in this kernel (r6/r10 proven).
// blocks 0..511   : sdw (+ asm keep-alive on win[])
// blocks 512..767 : xT bf16 swizzle prep
// blocks 768..775 : wT bf16 swizzle prep
// blocks 776..815 : passthrough channels 128..132
// ---------------------------------------------------------------------------
__global__ __launch_bounds__(512) void prep_sdw_kernel(
    const float* __restrict__ x, const float* __restrict__ cw,
    const float* __restrict__ sk, unsigned* __restrict__ xT,
    unsigned* __restrict__ wT, unsigned short* __restrict__ sdwb,
    float* __restrict__ sdwpart, float* __restrict__ out)
{
    int bl = blockIdx.x;
    int tid = threadIdx.x;

    if (bl < 512) {
        int chg = bl >> 5;              // 0..15 (channel group of 8)
        int slice = bl & 31;            // 0..31
        int pix = slice * 512 + tid;    // 0..16383
        int b = pix >> 10;
        int hw = pix & 1023;
        int h = hw >> 5, w = hw & 31;

        float win[45];
#pragma unroll
        for (int ch = 0; ch < 5; ++ch) {
            const float* xb = x + (((size_t)b * CT + CIN + ch) << 10);
#pragma unroll
            for (int ki = 0; ki < 3; ++ki) {
                int rr = h + ki - 1;
                rr = rr < 0 ? 0 : (rr > 31 ? 31 : rr);
                const float* rp = xb + (rr << 5);
#pragma unroll
                for (int kj = 0; kj < 3; ++kj) {
                    int cc = w + kj - 1;
                    cc = cc < 0 ? 0 : (cc > 31 ? 31 : cc);
                    win[ch * 9 + ki * 3 + kj] = rp[cc];
                }
            }
        }
#pragma unroll
        for (int ch = 0; ch < 2; ++ch) {
            float c = win[ch * 9 + 4];
#pragma unroll
            for (int k = 0; k < 9; ++k) win[ch * 9 + k] -= c;
        }
#pragma unroll
        for (int q = 0; q < 45; ++q) asm volatile("" : "+v"(win[q]));

        int wid = tid >> 6;
        int wslot = slice * 8 + wid;    // 0..255 per channel
        for (int j = 0; j < 8; ++j) {
            int ch = chg * 8 + j;       // uniform across the block
            const float* kk = sk + (size_t)ch * 45;
            float s = 0.f;
#pragma unroll
            for (int q = 0; q < 45; ++q) s += fabsf(win[q] - kk[q]);
            unsigned u = __float_as_uint(s);
            u += 0x7fffu + ((u >> 16) & 1u);
            sdwb[(((size_t)b * NO + ch) << 10) + hw] = (unsigned short)(u >> 16);
            float sr = __uint_as_float(u & 0xffff0000u);
            float ps = sr, ps2 = sr * sr;
#pragma unroll
            for (int off = 32; off; off >>= 1) {
                ps  += __shfl_xor(ps, off);
                ps2 += __shfl_xor(ps2, off);
            }
            if ((tid & 63) == 0) {
                sdwpart[((size_t)ch * 256 + wslot) * 2]     = ps;
                sdwpart[((size_t)ch * 256 + wslot) * 2 + 1] = ps2;
            }
        }
    } else if (bl < 768) {
        int v = (bl - 512) * 512 + tid;     // 0..131071
        int blk2 = v >> 8;                  // b*32 + h
        int t2 = v & 255;
        int b = blk2 >> 5, h = blk2 & 31;
        int w = t2 & 31, cp0 = t2 >> 5;
        const float* xr = x + (((size_t)b * CT) << 10) + h * 32 + w;
        unsigned* dst = xT + (size_t)blk2 * 1024 + w * 32;
        int sw = (w & 7) << 2;
#pragma unroll
        for (int r = 0; r < 4; ++r) {
            int cp = cp0 + r * 8;
            dst[cp ^ sw] = pack_bf16(xr[(size_t)(2 * cp) << 10],
                                     xr[(size_t)(2 * cp + 1) << 10]);
        }
    } else if (bl < 776) {
        int tg = (bl - 768) * 512 + tid;    // 0..4095
        int o = tg >> 5, cp = tg & 31;
        int sw = (o & 7) << 2;
#pragma unroll
        for (int tap = 0; tap < 9; ++tap) {
            float v0 = cw[((size_t)o * CIN + 2 * cp) * 9 + tap];
            float v1 = cw[((size_t)o * CIN + 2 * cp + 1) * 9 + tap];
            wT[tap * 4096 + o * 32 + (cp ^ sw)] = pack_bf16(v0, v1);
        }
    } else {
        int idx = (bl - 776) * 512 + tid;   // 0..20479 quads
        int q = idx & 255;
        int c = (idx >> 8) % 5;
        int b = (idx >> 8) / 5;
        ((float4*)out)[((size_t)b * OUTC + NO + c) * 256 + q] =
            ((const float4*)x)[((size_t)b * CT + CIN + c) * 256 + q];
    }
}

// ---------------------------------------------------------------------------
// D2: conv as 9 accumulated MFMA GEMMs, triple-buffered W ring + counted
// vmcnt (r9/r10, proven). Epilogue writes bf16 conv_out to ws (convb) and
// computes BN partials from the rounded values. 256 blocks x 512 thr.
// ---------------------------------------------------------------------------
__global__ __launch_bounds__(512) void conv_mfma_kernel(
    const char* __restrict__ xT, const char* __restrict__ wT,
    unsigned short* __restrict__ convb, float* __restrict__ convpart)
{
    __shared__ __align__(16) char smem[65536];
    char* Xs = smem;                    // 16 KB
    char* Wb0 = smem + 16384;           // 3 x 16 KB W ring
    char* Wb1 = smem + 32768;
    char* Wb2 = smem + 49152;

    int bid = blockIdx.x;
    int b = bid >> 4;
    int h0 = (bid & 15) * 2;

    int tid = threadIdx.x;
    int lane = tid & 63;
    int wid = tid >> 6;
    int lo = lane & 15, g = lane >> 4;
    int ks = wid >> 2;
    int mg = (wid >> 1) & 1;
    int ng = wid & 1;

    // ---- prologue: stage X, W0, W1 (6 outstanding loads per thread) ----
#pragma unroll
    for (int q = 0; q < 2; ++q) {
        int ch = wid * 2 + q;
        int s = ch >> 2;
        int srch = h0 - 1 + s; srch = srch < 0 ? 0 : (srch > 31 ? 31 : srch);
        gload16(xT + ((size_t)(b * 32 + srch)) * 4096 + (ch & 3) * 1024 + lane * 16,
                Xs + ch * 1024);
    }
#pragma unroll
    for (int q = 0; q < 2; ++q) {
        int ch = wid * 2 + q;
        gload16(wT + ch * 1024 + lane * 16, Wb0 + ch * 1024);
    }
#pragma unroll
    for (int q = 0; q < 2; ++q) {
        int ch = wid * 2 + q;
        gload16(wT + 16384 + ch * 1024 + lane * 16, Wb1 + ch * 1024);
    }

    int acol[2][3];
#pragma unroll
    for (int i = 0; i < 2; ++i)
#pragma unroll
        for (int kj = 0; kj < 3; ++kj) {
            int cin = i * 16 + lo + kj - 1;
            cin = cin < 0 ? 0 : (cin > 31 ? 31 : cin);
            acol[i][kj] = cin * 128 + ((ks * 64 + g * 16) ^ ((cin & 7) << 4));
        }
    int boff[4];
#pragma unroll
    for (int n = 0; n < 4; ++n) {
        int o = ng * 64 + n * 16 + lo;
        boff[n] = o * 128 + ((ks * 64 + g * 16) ^ ((o & 7) << 4));
    }

    f32x4 acc[2][4];
#pragma unroll
    for (int i = 0; i < 2; ++i)
#pragma unroll
        for (int n = 0; n < 4; ++n) acc[i][n] = (f32x4){0.f, 0.f, 0.f, 0.f};

    // ---- pipelined K-loop over 9 taps ----
#pragma unroll
    for (int tap = 0; tap < 9; ++tap) {
        int ki = tap / 3, kj = tap % 3;
        if (tap == 8) asm volatile("s_waitcnt vmcnt(0)" ::: "memory");
        else          asm volatile("s_waitcnt vmcnt(2)" ::: "memory");
        __builtin_amdgcn_sched_barrier(0);
        __builtin_amdgcn_s_barrier();
        __builtin_amdgcn_sched_barrier(0);
        if (tap + 2 < 9) {
            char* wn = ((tap + 2) % 3 == 0) ? Wb0 : ((tap + 2) % 3 == 1) ? Wb1 : Wb2;
#pragma unroll
            for (int q = 0; q < 2; ++q) {
                int ch = wid * 2 + q;
                gload16(wT + (size_t)(tap + 2) * 16384 + ch * 1024 + lane * 16,
                        wn + ch * 1024);
            }
        }
        const char* wc = (tap % 3 == 0) ? Wb0 : (tap % 3 == 1) ? Wb1 : Wb2;
        bf16x8 a0 = *(const bf16x8*)(Xs + (mg + ki) * 4096 + acol[0][kj]);
        bf16x8 a1 = *(const bf16x8*)(Xs + (mg + ki) * 4096 + acol[1][kj]);
#pragma unroll
        for (int n = 0; n < 4; ++n) {
            bf16x8 bv = *(const bf16x8*)(wc + boff[n]);
            acc[0][n] = __builtin_amdgcn_mfma_f32_16x16x32_bf16(a0, bv, acc[0][n], 0, 0, 0);
            acc[1][n] = __builtin_amdgcn_mfma_f32_16x16x32_bf16(a1, bv, acc[1][n], 0, 0, 0);
        }
    }
    __syncthreads();

    // ---- epilogue: combine ci-halves via LDS, store bf16, BN partials ----
    float* T = (float*)smem;   // [64][129] f32 = 33 KB (ring buffers dead)
    if (ks == 1) {
#pragma unroll
        for (int i = 0; i < 2; ++i)
#pragma unroll
            for (int n = 0; n < 4; ++n)
#pragma unroll
                for (int r = 0; r < 4; ++r) {
                    int pixel = (mg * 2 + i) * 16 + g * 4 + r;
                    int o = ng * 64 + n * 16 + lo;
                    T[pixel * 129 + o] = acc[i][n][r];
                }
    }
    __syncthreads();
    if (ks == 0) {
#pragma unroll
        for (int i = 0; i < 2; ++i)
#pragma unroll
            for (int n = 0; n < 4; ++n)
#pragma unroll
                for (int r = 0; r < 4; ++r) {
                    int pixel = (mg * 2 + i) * 16 + g * 4 + r;
                    int o = ng * 64 + n * 16 + lo;
                    T[pixel * 129 + o] += acc[i][n][r];
                }
    }
    __syncthreads();
    unsigned short* cbase = convb + (((size_t)b * NO) << 10) + h0 * 32;
#pragma unroll
    for (int r = 0; r < 4; ++r) {
        int o = r * 32 + (tid >> 4);
        int pq = tid & 15;
        float4 v;
        v.x = T[(pq * 4 + 0) * 129 + o];
        v.y = T[(pq * 4 + 1) * 129 + o];
        v.z = T[(pq * 4 + 2) * 129 + o];
        v.w = T[(pq * 4 + 3) * 129 + o];
        uint2 pk;
        pk.x = pack_bf16(v.x, v.y);
        pk.y = pack_bf16(v.z, v.w);
        *(uint2*)(cbase + ((size_t)o << 10) + pq * 4) = pk;
        float rx = bf16rt(v.x), ry = bf16rt(v.y);
        float rz = bf16rt(v.z), rw = bf16rt(v.w);
        float s  = rx + ry + rz + rw;
        float s2 = rx * rx + ry * ry + rz * rz + rw * rw;
#pragma unroll
        for (int off = 1; off < 16; off <<= 1) {
            s  += __shfl_xor(s, off);
            s2 += __shfl_xor(s2, off);
        }
        if (pq == 0) {
            convpart[((size_t)o * 256 + bid) * 2]     = s;
            convpart[((size_t)o * 256 + bid) * 2 + 1] = s2;
        }
    }
}

// ---------------------------------------------------------------------------
// D3: per-block stats reduce (8 channels) + fused BN/relu finalize reading
// bf16 conv/sdw (uint4 = 8 bf16), writing fp32 out once. 256 blk x 512 thr.
// ---------------------------------------------------------------------------
__global__ __launch_bounds__(512) void final_kernel(
    const unsigned short* __restrict__ sdwb,
    const unsigned short* __restrict__ convb,
    const float* __restrict__ convpart, const float* __restrict__ sdwpart,
    float* __restrict__ out)
{
    __shared__ float st[32];      // [8][4]: cm, cis, sm, sis
    int bl = blockIdx.x;
    int tid = threadIdx.x;
    int b = bl >> 4;
    int o0 = (bl & 15) * 8;

    int lane = tid & 63;
    int wid = tid >> 6;           // wave wid reduces channel o0+wid
    {
        int ch = o0 + wid;
        double cs = 0.0, cs2 = 0.0, ss = 0.0, ss2 = 0.0;
#pragma unroll
        for (int q = 0; q < 4; ++q) {
            int slot = lane + q * 64;
            const float* cp = convpart + ((size_t)ch * 256 + slot) * 2;
            cs  += cp[0]; cs2 += cp[1];
            const float* sp = sdwpart + ((size_t)ch * 256 + slot) * 2;
            ss  += sp[0]; ss2 += sp[1];
        }
#pragma unroll
        for (int off = 32; off; off >>= 1) {
            cs  += __shfl_down(cs, off);
            cs2 += __shfl_down(cs2, off);
            ss  += __shfl_down(ss, off);
            ss2 += __shfl_down(ss2, off);
        }
        if (lane == 0) {
            double n = 16384.0;
            double cm = cs / n, cv = cs2 / n - cm * cm;
            double sm = ss / n, sv = ss2 / n - sm * sm;
            st[wid * 4]     = (float)cm;
            st[wid * 4 + 1] = (float)(1.0 / sqrt(cv + 1e-5));
            st[wid * 4 + 2] = (float)sm;
            st[wid * 4 + 3] = (float)(1.0 / sqrt(sv + 1e-5));
        }
    }
    __syncthreads();

#pragma unroll
    for (int k = 0; k < 2; ++k) {
        int ql = tid + k * 512;        // 0..1023
        int pl = ql >> 7;              // 0..7 -> channel
        int g8 = ql & 127;             // group of 8 pixels
        int o = o0 + pl;
        size_t ebase = (((size_t)b * NO + o) << 10) + g8 * 8;
        uint4 cu = *(const uint4*)(convb + ebase);
        uint4 su = *(const uint4*)(sdwb + ebase);
        float cm = st[pl * 4], cis = st[pl * 4 + 1];
        float sm = st[pl * 4 + 2], sis = st[pl * 4 + 3];
        float4 r0, r1;
        float cv, sv, mu, v;
        unsigned uc, us;
        uc = cu.x; us = su.x;
        cv = __uint_as_float(uc << 16); sv = __uint_as_float(us << 16);
        mu = (sv - sm) * sis; mu = mu > 0.f ? mu : 0.f;
        v = (cv - cm) * cis - mu; r0.x = v > 0.f ? v : 0.f;
        cv = __uint_as_float(uc & 0xffff0000u); sv = __uint_as_float(us & 0xffff0000u);
        mu = (sv - sm) * sis; mu = mu > 0.f ? mu : 0.f;
        v = (cv - cm) * cis - mu; r0.y = v > 0.f ? v : 0.f;
        uc = cu.y; us = su.y;
        cv = __uint_as_float(uc << 16); sv = __uint_as_float(us << 16);
        mu = (sv - sm) * sis; mu = mu > 0.f ? mu : 0.f;
        v = (cv - cm) * cis - mu; r0.z = v > 0.f ? v : 0.f;
        cv = __uint_as_float(uc & 0xffff0000u); sv = __uint_as_float(us & 0xffff0000u);
        mu = (sv - sm) * sis; mu = mu > 0.f ? mu : 0.f;
        v = (cv - cm) * cis - mu; r0.w = v > 0.f ? v : 0.f;
        uc = cu.z; us = su.z;
        cv = __uint_as_float(uc << 16); sv = __uint_as_float(us << 16);
        mu = (sv - sm) * sis; mu = mu > 0.f ? mu : 0.f;
        v = (cv - cm) * cis - mu; r1.x = v > 0.f ? v : 0.f;
        cv = __uint_as_float(uc & 0xffff0000u); sv = __uint_as_float(us & 0xffff0000u);
        mu = (sv - sm) * sis; mu = mu > 0.f ? mu : 0.f;
        v = (cv - cm) * cis - mu; r1.y = v > 0.f ? v : 0.f;
        uc = cu.w; us = su.w;
        cv = __uint_as_float(uc << 16); sv = __uint_as_float(us << 16);
        mu = (sv - sm) * sis; mu = mu > 0.f ? mu : 0.f;
        v = (cv - cm) * cis - mu; r1.z = v > 0.f ? v : 0.f;
        cv = __uint_as_float(uc & 0xffff0000u); sv = __uint_as_float(us & 0xffff0000u);
        mu = (sv - sm) * sis; mu = mu > 0.f ? mu : 0.f;
        v = (cv - cm) * cis - mu; r1.w = v > 0.f ? v : 0.f;
        float* ob = out + (((size_t)b * OUTC + o) << 10) + g8 * 8;
        *(float4*)ob = r0;
        *(float4*)(ob + 4) = r1;
    }
}

extern "C" void kernel_launch(void* const* d_in, const int* in_sizes, int n_in,
                              void* d_out, int out_size, void* d_ws, size_t ws_size,
                              hipStream_t stream)
{
    const float* x  = (const float*)d_in[0];
    const float* cw = (const float*)d_in[1];
    const float* sk = (const float*)d_in[3];
    float* out = (float*)d_out;

    unsigned short* sdwb  = (unsigned short*)d_ws;                     // 4 MB
    unsigned short* convb = (unsigned short*)((char*)d_ws + 0x400000); // 4 MB
    unsigned* xT       = (unsigned*)((char*)d_ws + 0x810000);   // 2 MB
    unsigned* wT       = (unsigned*)((char*)d_ws + 0xA10000);   // 144 KB
    float*    convpart = (float*)((char*)d_ws + 0xA40000);      // 256 KB
    float*    sdwpart  = (float*)((char*)d_ws + 0xA80000);      // 256 KB

    prep_sdw_kernel<<<816, 512, 0, stream>>>(x, cw, sk, xT, wT, sdwb, sdwpart, out);
    conv_mfma_kernel<<<256, 512, 0, stream>>>((const char*)xT, (const char*)wT,
                                              convb, convpart);
    final_kernel   <<<256, 512, 0, stream>>>(sdwb, convb, convpart, sdwpart, out);
}